// Round 4
// baseline (85.354 us; speedup 1.0000x reference)
//
#include <hip/hip_runtime.h>

#define NBINS 51
#define NTT   64          // 1024/16 tiles per dimension
#define TILE  16
#define DV4   32          // 128 floats = 32 float4 per row
#define NBLK  (NTT * (NTT + 1) / 2)   // 2080
#define NCOPY 16
#define HSTR  103
#define NSPLIT 8          // split global hist copies (cuts atomic chains 8x)

// ---------------------------------------------------------------------------
// Kernel 1: one wave per 16x16 pair tile (bi <= bj), 2x2 microtile per lane.
// Matrix operands read DIRECTLY from global (x = 512 KB, L1/L2-resident;
// 8-way same-address lanes coalesce; deep vmcnt pipelining) — no LDS tile,
// no barriers, high occupancy. R0-R3 showed the LDS-staged version was
// latency-bound at 2 waves/SIMD (VALUBusy 10%, Occ 7.6%) regardless of
// histogram scheme.
// LDS only for the 16-copy privatized histogram (native ds_add_f32).
// ---------------------------------------------------------------------------
__global__ __launch_bounds__(64, 4) void pair_hist_kernel(
    const float* __restrict__ x,
    const int*   __restrict__ labels,
    float*       __restrict__ ghist)   // [NSPLIT][2*NBINS]
{
    __shared__ float shist[NCOPY * HSTR];

    // Decode upper-triangular tile pair (bi <= bj).
    int rem = blockIdx.x;
    int bi = 0;
    while (rem >= NTT - bi) { rem -= NTT - bi; ++bi; }
    const int bj = bi + rem;

    const int t = threadIdx.x;         // 0..63
    for (int k = t; k < NCOPY * HSTR; k += 64) shist[k] = 0.0f;

    const int tx = t & 7;              // col microtile
    const int ty = t >> 3;             // row microtile
    const int gi0 = bi * TILE + ty * 2;
    const int gj0 = bj * TILE + tx * 2;

    const float4* a0p = (const float4*)(x + (size_t)gi0 * 128);
    const float4* a1p = a0p + DV4;
    const float4* b0p = (const float4*)(x + (size_t)gj0 * 128);
    const float4* b1p = b0p + DV4;

    float acc00 = 0.f, acc01 = 0.f, acc10 = 0.f, acc11 = 0.f;
    #pragma unroll 4
    for (int d = 0; d < DV4; ++d) {
        float4 a0 = a0p[d];
        float4 a1 = a1p[d];
        float4 b0 = b0p[d];
        float4 b1 = b1p[d];
        acc00 += a0.x*b0.x + a0.y*b0.y + a0.z*b0.z + a0.w*b0.w;
        acc01 += a0.x*b1.x + a0.y*b1.y + a0.z*b1.z + a0.w*b1.w;
        acc10 += a1.x*b0.x + a1.y*b0.y + a1.z*b0.z + a1.w*b0.w;
        acc11 += a1.x*b1.x + a1.y*b1.y + a1.z*b1.z + a1.w*b1.w;
    }

    const int la0 = labels[gi0], la1 = labels[gi0 + 1];
    const int lb0 = labels[gj0], lb1 = labels[gj0 + 1];
    const int las[2] = {la0, la1};
    const int lbs[2] = {lb0, lb1};

    __syncthreads();   // hist zero-init visible (single wave: cheap)

    const float BW = 2.0f / (NBINS - 1);
    float accs[2][2] = {{acc00, acc01}, {acc10, acc11}};
    float* myh = &shist[(t & (NCOPY - 1)) * HSTR];

    #pragma unroll
    for (int r = 0; r < 2; ++r) {
        #pragma unroll
        for (int c = 0; c < 2; ++c) {
            int gi = gi0 + r;
            int gj = gj0 + c;
            if (gi < gj) {
                float s = accs[r][c];
                int b = (int)floorf((s + 1.0f) / BW);
                b = min(max(b, 0), NBINS - 1);
                float v = (float)b * BW - 1.0f;
                float wlo = (v + BW - s) / BW;
                float whi = (s - v) / BW;
                int bh = min(b + 1, NBINS - 1);
                int base = (las[r] == lbs[c]) ? 0 : NBINS;
                unsafeAtomicAdd(&myh[base + b],  wlo);   // native ds_add_f32
                unsafeAtomicAdd(&myh[base + bh], whi);
            }
        }
    }

    __syncthreads();
    // Reduce 16 copies; skip empty bins (most blocks touch ~15 of 102);
    // 8-way split destination cuts same-address chains to ~65.
    float* gh = ghist + (blockIdx.x & (NSPLIT - 1)) * (2 * NBINS);
    for (int bin = t; bin < 2 * NBINS; bin += 64) {
        float s = 0.f;
        #pragma unroll
        for (int c = 0; c < NCOPY; ++c) s += shist[c * HSTR + bin];
        if (s != 0.0f) unsafeAtomicAdd(&gh[bin], s);
    }
}

// ---------------------------------------------------------------------------
// Kernel 2: one wave. Merge 8 split hists, sums, CDF (inclusive scan), loss.
// sum(hist) over bins == pair count (w_lo + w_hi == 1), normalizers free.
// ---------------------------------------------------------------------------
__global__ void finalize_kernel(const float* __restrict__ gh,
                                float* __restrict__ out)
{
    int t = threadIdx.x;   // 64 threads
    float hp = 0.f, hn = 0.f;
    if (t < NBINS) {
        #pragma unroll
        for (int c = 0; c < NSPLIT; ++c) {
            hp += gh[c * (2 * NBINS) + t];
            hn += gh[c * (2 * NBINS) + NBINS + t];
        }
    }

    float sp = hp, sn = hn;
    #pragma unroll
    for (int off = 32; off > 0; off >>= 1) {
        sp += __shfl_xor(sp, off, 64);
        sn += __shfl_xor(sn, off, 64);
    }

    float cdf = hp;
    #pragma unroll
    for (int off = 1; off < 64; off <<= 1) {
        float v = __shfl_up(cdf, off, 64);
        if (t >= off) cdf += v;
    }

    float contrib = hn * cdf;
    #pragma unroll
    for (int off = 32; off > 0; off >>= 1)
        contrib += __shfl_xor(contrib, off, 64);

    if (t == 0) out[0] = contrib / (sp * sn);
}

extern "C" void kernel_launch(void* const* d_in, const int* in_sizes, int n_in,
                              void* d_out, int out_size, void* d_ws, size_t ws_size,
                              hipStream_t stream)
{
    const float* x      = (const float*)d_in[0];
    const int*   labels = (const int*)d_in[1];
    float*       ghist  = (float*)d_ws;   // [NSPLIT][2*NBINS]

    hipMemsetAsync(ghist, 0, NSPLIT * 2 * NBINS * sizeof(float), stream);
    pair_hist_kernel<<<NBLK, 64, 0, stream>>>(x, labels, ghist);
    finalize_kernel<<<1, 64, 0, stream>>>(ghist, (float*)d_out);
}

// Round 5
// 80.041 us; speedup vs baseline: 1.0664x; 1.0664x over previous
//
#include <hip/hip_runtime.h>

#define NBINS 51
#define NT    32          // tiles per dimension (1024 / 32)
#define TILE  32          // rows per tile
#define DV4   32          // 128 floats = 32 float4 per row
#define NBLK  (NT * (NT + 1) / 2)   // 528
#define NCOPY 16
#define HSTR  103         // hist copy stride (odd -> banks decorrelated)

// ---------------------------------------------------------------------------
// Measured-best structure (R3, 78.9 us total).
// Timing anatomy (from R1-R4 profiles): the harness's 268 MB d_ws poison
// fill costs ~40 us, and the NEXT dispatch absorbs a ~38 us drain/fence
// stall no matter what it does (a 14.85 KB fill showed 39.68 us). The tiny
// ghist memset below is that drain absorber; the real kernels run ~1-3 us
// after it. Total is therefore dominated by harness-imposed overhead.
// ---------------------------------------------------------------------------
__global__ __launch_bounds__(256) void pair_hist_kernel(
    const float* __restrict__ x,
    const int*   __restrict__ labels,
    float*       __restrict__ ghist)
{
    __shared__ float4 As[TILE][DV4];   // chunk c stored at c ^ ((row>>1)&7)
    __shared__ float4 Bs[TILE][DV4];
    __shared__ int    la[TILE], lb[TILE];
    __shared__ float  shist[NCOPY * HSTR];

    // Decode upper-triangular tile pair (bi <= bj).
    int rem = blockIdx.x;
    int bi = 0;
    while (rem >= NT - bi) { rem -= NT - bi; ++bi; }
    const int bj = bi + rem;

    const int t = threadIdx.x;
    for (int k = t; k < NCOPY * HSTR; k += 256) shist[k] = 0.0f;

    const float4* xv = (const float4*)x;
    #pragma unroll
    for (int k = 0; k < 4; ++k) {
        int e = t + 256 * k;
        int r = e >> 5;
        int c = e & 31;
        int sw = c ^ ((r >> 1) & 7);
        As[r][sw] = xv[(bi * TILE + r) * DV4 + c];
        Bs[r][sw] = xv[(bj * TILE + r) * DV4 + c];
    }
    if (t < TILE) {
        la[t] = labels[bi * TILE + t];
        lb[t] = labels[bj * TILE + t];
    }
    __syncthreads();

    const int tx = t & 15;
    const int ty = t >> 4;
    const int i0 = ty * 2, j0 = tx * 2;
    const int kA = ty & 7;
    const int kB = tx & 7;

    float acc00 = 0.f, acc01 = 0.f, acc10 = 0.f, acc11 = 0.f;
    #pragma unroll 4
    for (int d4 = 0; d4 < DV4; ++d4) {
        float4 a0 = As[i0    ][d4 ^ kA];
        float4 a1 = As[i0 + 1][d4 ^ kA];
        float4 b0 = Bs[j0    ][d4 ^ kB];
        float4 b1 = Bs[j0 + 1][d4 ^ kB];
        acc00 += a0.x*b0.x + a0.y*b0.y + a0.z*b0.z + a0.w*b0.w;
        acc01 += a0.x*b1.x + a0.y*b1.y + a0.z*b1.z + a0.w*b1.w;
        acc10 += a1.x*b0.x + a1.y*b0.y + a1.z*b0.z + a1.w*b0.w;
        acc11 += a1.x*b1.x + a1.y*b1.y + a1.z*b1.z + a1.w*b1.w;
    }

    const float BW = 2.0f / (NBINS - 1);
    float accs[2][2] = {{acc00, acc01}, {acc10, acc11}};
    float* myh = &shist[(t & (NCOPY - 1)) * HSTR];

    #pragma unroll
    for (int r = 0; r < 2; ++r) {
        #pragma unroll
        for (int c = 0; c < 2; ++c) {
            int gi = bi * TILE + i0 + r;
            int gj = bj * TILE + j0 + c;
            if (gi < gj) {
                float s = accs[r][c];
                int b = (int)floorf((s + 1.0f) / BW);
                b = min(max(b, 0), NBINS - 1);
                float v = (float)b * BW - 1.0f;
                float wlo = (v + BW - s) / BW;
                float whi = (s - v) / BW;
                int bh = min(b + 1, NBINS - 1);
                int base = (la[i0 + r] == lb[j0 + c]) ? 0 : NBINS;
                unsafeAtomicAdd(&myh[base + b],  wlo);   // native ds_add_f32
                unsafeAtomicAdd(&myh[base + bh], whi);
            }
        }
    }

    __syncthreads();
    // Reduce 16 copies; one native global atomic per bin.
    if (t < 2 * NBINS) {
        float s = 0.f;
        #pragma unroll
        for (int c = 0; c < NCOPY; ++c) s += shist[c * HSTR + t];
        unsafeAtomicAdd(&ghist[t], s);                   // native global_atomic_add_f32
    }
}

// ---------------------------------------------------------------------------
// Kernel 2: one wave. Sums, CDF of pos hist (inclusive scan), loss.
// sum(hist) over bins == pair count (w_lo + w_hi == 1 per pair), so the
// normalizers come for free.
// ---------------------------------------------------------------------------
__global__ void finalize_kernel(const float* __restrict__ gh,
                                float* __restrict__ out)
{
    int t = threadIdx.x;   // 64 threads
    float hp = (t < NBINS) ? gh[t]         : 0.0f;
    float hn = (t < NBINS) ? gh[NBINS + t] : 0.0f;

    float sp = hp, sn = hn;
    #pragma unroll
    for (int off = 32; off > 0; off >>= 1) {
        sp += __shfl_xor(sp, off, 64);
        sn += __shfl_xor(sn, off, 64);
    }

    float cdf = hp;
    #pragma unroll
    for (int off = 1; off < 64; off <<= 1) {
        float v = __shfl_up(cdf, off, 64);
        if (t >= off) cdf += v;
    }

    float contrib = hn * cdf;
    #pragma unroll
    for (int off = 32; off > 0; off >>= 1)
        contrib += __shfl_xor(contrib, off, 64);

    if (t == 0) out[0] = contrib / (sp * sn);
}

extern "C" void kernel_launch(void* const* d_in, const int* in_sizes, int n_in,
                              void* d_out, int out_size, void* d_ws, size_t ws_size,
                              hipStream_t stream)
{
    const float* x      = (const float*)d_in[0];
    const int*   labels = (const int*)d_in[1];
    float*       ghist  = (float*)d_ws;

    // Tiny memset doubles as the post-poison drain absorber (see header note).
    hipMemsetAsync(ghist, 0, 2 * NBINS * sizeof(float), stream);
    pair_hist_kernel<<<NBLK, 256, 0, stream>>>(x, labels, ghist);
    finalize_kernel<<<1, 64, 0, stream>>>(ghist, (float*)d_out);
}